// Round 3
// baseline (55.618 us; speedup 1.0000x reference)
//
#include <hip/hip_runtime.h>
#include <math.h>

// Analytic evaluation of the QNN circuit expectation values (see R0 notes):
//
//   out(b,w) = <psi1| C1^ (⊗_q M_q) C1 |psi1>
//     psi1 = ⊗_q (cos(t_q/2), -i sin(t_q/2)),  t_q = x[b,q] + W[0,q]
//     M_q  = cos(th_q) Z + sin(th_q) Y  on wires Q_w (w=0 -> {1..15}, else {0..w}),
//            I elsewhere;  th_q = W[1,q]
//     C1   = ring of CNOTs = prefix-XOR basis permutation
//
// 4-state (p',p) transfer-matrix chain over q=1..15, 4-branch periodic
// boundary (a0',a0) at q=0; thread = (w, branch), block = sample.
// R2 change: libm sincosf -> native v_sin_f32/v_cos_f32 (__sinf/__cosf).
// Precision headroom: threshold 4.5e-4 abs, we were at 7.6e-6 with libm.

#define NQ 16
#define BATCH 32

__global__ __launch_bounds__(64) void qnn_transfer_kernel(
        const float* __restrict__ x,     // (32,16)
        const float* __restrict__ wt,    // (2,16)
        float* __restrict__ out)         // (32,16)
{
    const int b   = blockIdx.x;      // sample
    const int tid = threadIdx.x;     // w*4 + branch
    const int w   = tid >> 2;        // measured wire
    const int br  = tid & 3;         // boundary branch (alp<<1)|al
    const int al  = br & 1;          // a_0   (ket)
    const int alp = (br >> 1) & 1;   // a'_0  (bra)

    // Per-wire trig, computed once per block by 16 lanes (native HW trig).
    // phi_q(0)=pc[q] (real), phi_q(1)=-i*ps[q]; K_q=[[kc,-i ks],[i ks,-kc]]
    __shared__ float pc[NQ], ps[NQ], kc[NQ], ks[NQ];
    if (tid < NQ) {
        float t1 = 0.5f * (x[b * NQ + tid] + wt[tid]);  // (x + W[0,q])/2
        float th = wt[NQ + tid];                        // W[1,q]
        pc[tid] = __cosf(t1); ps[tid] = __sinf(t1);
        kc[tid] = __cosf(th); ks[tid] = __sinf(th);
    }
    __syncthreads();

    // Chain state V[(p'<<1)|p], complex, for this thread's boundary branch:
    // init V[br] = phi_0(al) * conj(phi_0(alp)), rest 0.
    //   br=0: c0^2 (re)   br=1: -i s0 c0   br=2: +i s0 c0   br=3: s0^2 (re)
    const float c0 = pc[0], s0 = ps[0];
    float v00r = (br == 0) ? c0 * c0 : 0.f, v00i = 0.f;
    float v01r = 0.f, v01i = (br == 1) ? -s0 * c0 : 0.f;
    float v10r = 0.f, v10i = (br == 2) ?  s0 * c0 : 0.f;
    float v11r = (br == 3) ? s0 * s0 : 0.f, v11i = 0.f;

    // Transfer steps q = 1..15:
    //   ket:  u_{p',r} = c*v_{p',r} + (-i s)*v_{p',r^1}
    //   bra:  z_{r',r} = c*u_{r',r} + (+i s)*u_{r'^1,r}
    //   gate: V_{r',r} = [M]_{r',r} * z_{r',r}
    //         M = [[a, -i e],[i e, d]], a=inQ?kc:1, e=inQ?ks:0, d=inQ?-kc:1
    #pragma unroll
    for (int q = 1; q < NQ; ++q) {
        const float c = pc[q], s = ps[q];
        const bool inQ = (w == 0) ? true : (q <= w);
        const float a = inQ ?  kc[q] : 1.f;
        const float e = inQ ?  ks[q] : 0.f;
        const float d = inQ ? -kc[q] : 1.f;

        // ket sum over p
        float u00r =  c * v00r + s * v01i, u00i =  c * v00i - s * v01r;
        float u01r =  s * v00i + c * v01r, u01i = -s * v00r + c * v01i;
        float u10r =  c * v10r + s * v11i, u10i =  c * v10i - s * v11r;
        float u11r =  s * v10i + c * v11r, u11i = -s * v10r + c * v11i;
        // bra sum over p' (conjugated phase: +i s)
        float z00r =  c * u00r - s * u10i, z00i =  c * u00i + s * u10r;
        float z01r =  c * u01r - s * u11i, z01i =  c * u01i + s * u11r;
        float z10r = -s * u00i + c * u10r, z10i =  s * u00r + c * u10i;
        float z11r = -s * u01i + c * u11r, z11i =  s * u01r + c * u11i;
        // elementwise gate factor
        v00r =  a * z00r;  v00i =  a * z00i;   // {a,0}  * z00
        v01r =  e * z01i;  v01i = -e * z01r;   // {0,-e} * z01
        v10r = -e * z10i;  v10i =  e * z10r;   // {0,+e} * z10
        v11r =  d * z11r;  v11i =  d * z11i;   // {d,0}  * z11
    }

    // Periodic boundary at q=0: b_0 = p_15 ^ a_0.
    // acc = sum_j Re( N_{bep^alp, be^al} * V[j] ), j=(bep<<1)|be
    //   N = [[A, -iB],[iB, D]]; contributions:
    //   (0,0): A*Vr  (0,1): B*Vi  (1,0): -B*Vi  (1,1): D*Vr
    const bool q0in = (w >= 1);
    const float A = q0in ?  kc[0] : 1.f;
    const float B = q0in ?  ks[0] : 0.f;
    const float D = q0in ? -kc[0] : 1.f;

    auto contrib = [&](int row, int col, float Vr, float Vi) -> float {
        return row ? (col ? D * Vr : -B * Vi)
                   : (col ? B * Vi :  A * Vr);
    };
    float acc = contrib(alp,     al,     v00r, v00i)   // j=0: be=0,bep=0
              + contrib(alp,     al ^ 1, v01r, v01i)   // j=1: be=1,bep=0
              + contrib(alp ^ 1, al,     v10r, v10i)   // j=2: be=0,bep=1
              + contrib(alp ^ 1, al ^ 1, v11r, v11i);  // j=3: be=1,bep=1

    // Sum the 4 boundary branches (lanes w*4+0..3, xor stays in-group).
    acc += __shfl_xor(acc, 1);
    acc += __shfl_xor(acc, 2);
    if (br == 0) out[b * NQ + w] = acc;
}

extern "C" void kernel_launch(void* const* d_in, const int* in_sizes, int n_in,
                              void* d_out, int out_size, void* d_ws, size_t ws_size,
                              hipStream_t stream) {
    const float* x  = (const float*)d_in[0];   // (32,16) float32
    const float* wt = (const float*)d_in[1];   // (2,16)  float32
    float* out = (float*)d_out;                // (32,16) float32
    (void)in_sizes; (void)n_in; (void)out_size; (void)d_ws; (void)ws_size;

    qnn_transfer_kernel<<<BATCH, 64, 0, stream>>>(x, wt, out);
}